// Round 17
// baseline (72.128 us; speedup 1.0000x reference)
//
#include <hip/hip_runtime.h>

#define NCAP 10     // capsule classes c
#define NB   256    // batch b
#define NN   1152   // route nodes n
#define KI   8      // input dim i
#define NO   16     // output dim o
#define NT   1024   // threads per block (16 waves: 8 build + 8 route)
#define TB   2      // batches per problem
#define NPROB 5     // problems per block (1280 / 256 blocks)
#define NBLK 256    // grid = 1 block per CU

typedef float v2f __attribute__((ext_vector_type(2)));

// Round-16 producer/consumer pipeline + depth-2 W/x register prefetch in the
// build stages. Round-16 lesson: 8 build waves (2/SIMD) with 12 loads in
// flight can't cover L2 latency at L1 rate -> route waves starved at
// barriers. Depth-2 prefetch doubles per-wave MLP (~24 loads in flight).
__global__ __launch_bounds__(NT, 4) void capsule_kernel(
    const float* __restrict__ x,    // [256,1152,8]
    const float* __restrict__ w,    // [10,1152,8,16]
    float* __restrict__ out)        // [10,256,16]
{
    __shared__ unsigned s_pr[2][TB * NN * 8];   // 2 x 72 KB priors (parity)
    __shared__ float s_bsw[8][TB][NO];          // build-wave iter-1 partials
    __shared__ float s_rp[2][8][TB][NO];        // route partials (iter parity)
    __shared__ float s_lse[2][8][TB];           // route exp-sums (iter parity)

    const int t = threadIdx.x, wv = t >> 6, lane = t & 63, bid = blockIdx.x;
    const int j = t & 3, g2 = t >> 2;           // build: o-quad, cluster 0..127
    const int rt = t - 512, rwv = wv - 8;       // route ids
    const int tb2 = (lane >> 4) & 1, oc = lane & 15;
    const int bl0 = lane & 1, bl1 = (lane >> 1) & 1,
              bl2v = (lane >> 2) & 1, bl3 = (lane >> 3) & 1;

    auto slotof = [](int n, int q) { return 2 * n + (q ^ ((n >> 2) & 1)); };
    auto squash = [&](float s_o) {
        float sq = s_o * s_o;
        sq += __shfl_xor(sq, 1); sq += __shfl_xor(sq, 2);
        sq += __shfl_xor(sq, 4); sq += __shfl_xor(sq, 8);
        return s_o * (sq / ((1.f + sq) * sqrtf(sq)));
    };

    #pragma unroll 1
    for (int k = 0; k <= NPROB; ++k) {
        const int parB = k & 1, parR = parB ^ 1;
        const bool do_build = (k < NPROB), do_route = (k >= 1);
        // problem->(c,b0): P&7 = bid&7 keeps same-c problems on one XCD
        const int Pb = k * NBLK + bid;
        const int swzB = (Pb & 7) * 160 + (Pb >> 3);
        const int cB = swzB >> 7, b0B = (swzB & 127) * 2;
        const int Pr = (k - 1) * NBLK + bid;
        const int swzR = (Pr & 7) * 160 + (Pr >> 3);
        const int cR = swzR >> 7, b0R = (swzR & 127) * 2;

        float bs[TB][4] = {{0.f,0.f,0.f,0.f},{0.f,0.f,0.f,0.f}};
        float logit[3][TB];
        float vo = 0.f;

        // ---- build helpers: depth-2 software pipeline over rounds ----
        auto load_wx = [&](int n, float4* wq, float4* xv) {
            const float4* wp = reinterpret_cast<const float4*>(
                w + ((size_t)cB * NN + n) * (KI * NO));
            #pragma unroll
            for (int i = 0; i < KI; ++i) wq[i] = wp[i * 4 + j];
            const float4* xp0 = reinterpret_cast<const float4*>(
                x + ((size_t)(b0B + 0) * NN + n) * KI);
            const float4* xp1 = reinterpret_cast<const float4*>(
                x + ((size_t)(b0B + 1) * NN + n) * KI);
            xv[0] = xp0[0]; xv[1] = xp0[1];
            xv[2] = xp1[0]; xv[3] = xp1[1];
        };
        auto proc = [&](int n, const float4* wq, const float4* xv) {
            float xs[TB][KI] = {
                {xv[0].x, xv[0].y, xv[0].z, xv[0].w,
                 xv[1].x, xv[1].y, xv[1].z, xv[1].w},
                {xv[2].x, xv[2].y, xv[2].z, xv[2].w,
                 xv[3].x, xv[3].y, xv[3].z, xv[3].w}};
            float acc[TB][4] = {{0.f,0.f,0.f,0.f},{0.f,0.f,0.f,0.f}};
            #pragma unroll
            for (int i = 0; i < KI; ++i)
                #pragma unroll
                for (int tb = 0; tb < TB; ++tb) {
                    acc[tb][0] = fmaf(xs[tb][i], wq[i].x, acc[tb][0]);
                    acc[tb][1] = fmaf(xs[tb][i], wq[i].y, acc[tb][1]);
                    acc[tb][2] = fmaf(xs[tb][i], wq[i].z, acc[tb][2]);
                    acc[tb][3] = fmaf(xs[tb][i], wq[i].w, acc[tb][3]);
                }
            const int q = j >> 1, h = j & 1;
            #pragma unroll
            for (int tb = 0; tb < TB; ++tb) {
                bs[tb][0] += acc[tb][0]; bs[tb][1] += acc[tb][1];
                bs[tb][2] += acc[tb][2]; bs[tb][3] += acc[tb][3];
                unsigned p0, p1;
                asm("v_cvt_pk_bf16_f32 %0, %1, %2"
                    : "=v"(p0) : "v"(acc[tb][0]), "v"(acc[tb][1]));
                asm("v_cvt_pk_bf16_f32 %0, %1, %2"
                    : "=v"(p1) : "v"(acc[tb][2]), "v"(acc[tb][3]));
                uint2 pk2; pk2.x = p0; pk2.y = p1;
                *reinterpret_cast<uint2*>(
                    &s_pr[parB][tb * (NN*8) + slotof(n, q) * 4 + h * 2]) = pk2;
            }
        };
        auto build_stage = [&](int n0, int n1, int n2) {
            float4 wqA[KI], wqB[KI], xvA[4], xvB[4];
            load_wx(n0, wqA, xvA);          // in flight during nothing (stage head)
            load_wx(n1, wqB, xvB);          // in flight during proc(n0)
            proc(n0, wqA, xvA);
            load_wx(n2, wqA, xvA);          // in flight during proc(n1)
            proc(n1, wqB, xvB);
            proc(n2, wqA, xvA);
        };

        auto route_iter = [&](bool first, int wpar) {
            #pragma unroll
            for (int tb = 0; tb < TB; ++tb) {
                v2f vv2[8];
                #pragma unroll
                for (int o2 = 0; o2 < 8; ++o2) {   // in-wave v broadcast
                    vv2[o2].x = __shfl(vo, tb * 16 + 2 * o2);
                    vv2[o2].y = __shfl(vo, tb * 16 + 2 * o2 + 1);
                }
                v2f sp2[8];
                #pragma unroll
                for (int p = 0; p < 8; ++p) sp2[p] = v2f{0.f, 0.f};
                float lse = 0.f;
                #pragma unroll
                for (int row = 0; row < 3; ++row) {
                    if (row < 2 || rt < 128) {     // waves 8,9 own the tail
                        const int n = row * 512 + rt;
                        const unsigned* base = &s_pr[parR][tb * (NN * 8)];
                        uint4 qa = *reinterpret_cast<const uint4*>(&base[slotof(n, 0) * 4]);
                        uint4 qb = *reinterpret_cast<const uint4*>(&base[slotof(n, 1) * 4]);
                        unsigned u[8] = {qa.x, qa.y, qa.z, qa.w, qb.x, qb.y, qb.z, qb.w};
                        v2f r2[8];
                        #pragma unroll
                        for (int op = 0; op < 8; ++op) {
                            r2[op].x = __uint_as_float(u[op] << 16);
                            r2[op].y = __uint_as_float(u[op] & 0xffff0000u);
                        }
                        v2f d2 = v2f{0.f, 0.f};
                        #pragma unroll
                        for (int op = 0; op < 8; ++op)
                            d2 = __builtin_elementwise_fma(r2[op], vv2[op], d2);
                        float lg = d2.x + d2.y;
                        if (!first) lg += logit[row][tb];
                        logit[row][tb] = lg;       // |logit| <~30: f32-safe
                        float e = __expf(lg);
                        lse += e;
                        v2f e2 = v2f{e, e};
                        #pragma unroll
                        for (int op = 0; op < 8; ++op)
                            sp2[op] = __builtin_elementwise_fma(e2, r2[op], sp2[op]);
                    }
                }
                float s = lse;
                s += __shfl_xor(s, 1);  s += __shfl_xor(s, 2);
                s += __shfl_xor(s, 4);  s += __shfl_xor(s, 8);
                s += __shfl_xor(s, 16); s += __shfl_xor(s, 32);
                if (lane == 0) s_lse[wpar][rwv][tb] = s;
                float g8[8];
                #pragma unroll
                for (int r = 0; r < 8; ++r) {
                    float keep = bl0 ? sp2[r].y : sp2[r].x;
                    float send = bl0 ? sp2[r].x : sp2[r].y;
                    g8[r] = keep + __shfl_xor(send, 1);
                }
                float g4[4];
                #pragma unroll
                for (int r = 0; r < 4; ++r) {
                    float keep = bl1 ? g8[2*r+1] : g8[2*r];
                    float send = bl1 ? g8[2*r]   : g8[2*r+1];
                    g4[r] = keep + __shfl_xor(send, 2);
                }
                float g2x[2];
                #pragma unroll
                for (int r = 0; r < 2; ++r) {
                    float keep = bl2v ? g4[2*r+1] : g4[2*r];
                    float send = bl2v ? g4[2*r]   : g4[2*r+1];
                    g2x[r] = keep + __shfl_xor(send, 4);
                }
                float g1;
                {
                    float keep = bl3 ? g2x[1] : g2x[0];
                    float send = bl3 ? g2x[0] : g2x[1];
                    g1 = keep + __shfl_xor(send, 8);
                }
                g1 += __shfl_xor(g1, 16);
                g1 += __shfl_xor(g1, 32);
                if (lane < NO) s_rp[wpar][rwv][tb][lane] = g1;
            }
        };

        // ---------------- STAGE 1: build r0-2 | fin0 + iter1 ----------------
        if (t < 512) {
            if (do_build) build_stage(g2, 128 + g2, 256 + g2);
        } else if (do_route) {
            float acc = 0.f;
            #pragma unroll
            for (int w2 = 0; w2 < 8; ++w2) acc += s_bsw[w2][tb2][oc];
            vo = squash(acc / (float)NN);       // softmax(0) is uniform
            route_iter(true, 1);
        }
        __syncthreads();
        // ---------------- STAGE 2: build r3-5 | fin1 + iter2 ----------------
        if (t < 512) {
            if (do_build) build_stage(384 + g2, 512 + g2, 640 + g2);
        } else if (do_route) {
            float acc = 0.f, lt = 0.f;
            #pragma unroll
            for (int w2 = 0; w2 < 8; ++w2) {
                acc += s_rp[1][w2][tb2][oc]; lt += s_lse[1][w2][tb2];
            }
            vo = squash(acc / lt);
            route_iter(false, 0);
        }
        __syncthreads();
        // ---------------- STAGE 3: build r6-8 + bs | fin2 -> out ------------
        if (t < 512) {
            if (do_build) {
                build_stage(768 + g2, 896 + g2, 1024 + g2);
                #pragma unroll
                for (int tb = 0; tb < TB; ++tb)
                    #pragma unroll
                    for (int kk = 0; kk < 4; ++kk) {
                        float s = bs[tb][kk];
                        s += __shfl_xor(s, 4);  s += __shfl_xor(s, 8);
                        s += __shfl_xor(s, 16); s += __shfl_xor(s, 32);
                        bs[tb][kk] = s;
                    }
                if (lane < 4) {
                    #pragma unroll
                    for (int tb = 0; tb < TB; ++tb) {
                        s_bsw[wv][tb][4*lane+0] = bs[tb][0];
                        s_bsw[wv][tb][4*lane+1] = bs[tb][1];
                        s_bsw[wv][tb][4*lane+2] = bs[tb][2];
                        s_bsw[wv][tb][4*lane+3] = bs[tb][3];
                    }
                }
            }
        } else if (do_route) {
            float acc = 0.f, lt = 0.f;
            #pragma unroll
            for (int w2 = 0; w2 < 8; ++w2) {
                acc += s_rp[0][w2][tb2][oc]; lt += s_lse[0][w2][tb2];
            }
            vo = squash(acc / lt);
            if (wv == 8 && lane < 32)
                out[((size_t)cR * NB + b0R + tb2) * NO + oc] = vo;
        }
        __syncthreads();
    }
}

extern "C" void kernel_launch(void* const* d_in, const int* in_sizes, int n_in,
                              void* d_out, int out_size, void* d_ws, size_t ws_size,
                              hipStream_t stream) {
    const float* x = (const float*)d_in[0];
    const float* w = (const float*)d_in[1];
    float* out = (float*)d_out;
    capsule_kernel<<<dim3(NBLK), dim3(NT), 0, stream>>>(x, w, out);
}